// Round 4
// baseline (358.751 us; speedup 1.0000x reference)
//
#include <hip/hip_runtime.h>
#include <stdint.h>
#include <stddef.h>

typedef __attribute__((ext_vector_type(8))) short short8;
typedef __attribute__((ext_vector_type(4))) float f32x4;

#define N_IMG 32
#define C_IN  256
#define HH    64
#define WW    64
#define O_OUT 256
#define HP    66
#define WP    66

#define QX_ELEMS (N_IMG*HP*WP*C_IN)      // 35,684,352
#define QX_BYTES ((size_t)QX_ELEMS*2)    // 71,368,704
#define QW_ELEMS (9*O_OUT*C_IN)          // 589,824

// ---------- quantization helpers (match jnp reference bit-for-bit) ----------

// nearest E2M1 magnitude; ties round up (jnp.digitize right=False: a==mid -> upper)
__device__ __forceinline__ float e2m1_mag(float a) {
    return a < 0.25f ? 0.0f
         : a < 0.75f ? 0.5f
         : a < 1.25f ? 1.0f
         : a < 1.75f ? 1.5f
         : a < 2.5f  ? 2.0f
         : a < 3.5f  ? 3.0f
         : a < 5.0f  ? 4.0f : 6.0f;
}

// scale = 2^ceil(log2(max(amax,1e-30)/6)), or 1.0 if amax==0; also exact 1/scale.
__device__ __forceinline__ void blk_scale2(float amax, float& s, float& inv) {
    float ac = fmaxf(amax, 1e-30f);
    int e;
    float m = frexpf(ac, &e);
    int ex = (m > 0.75f) ? (e - 2) : (e - 3);
    if (amax > 0.0f) { s = ldexpf(1.0f, ex); inv = ldexpf(1.0f, -ex); }
    else             { s = 1.0f; inv = 1.0f; }
}

// E2M1-grid * pow2 -> 1 mantissa bit -> exact in bf16 (truncate == round)
__device__ __forceinline__ unsigned short to_bf16_bits(float v) {
    union { float f; unsigned int u; } cv; cv.f = v;
    return (unsigned short)(cv.u >> 16);
}

// ---------- halo zero: only the 4.3 MB border of qx (replaces 71 MB memset) ----------
__global__ __launch_bounds__(256) void halo_zero_kernel(unsigned short* __restrict__ qx) {
    int id = blockIdx.x * 256 + threadIdx.x;
    size_t off;
    if (id < 135168) {
        int n = id / 4224, r = id % 4224;
        int h = (r / 2112) * 65;
        int k = r % 2112;
        off = (((size_t)(n*HP + h)) * WP) * C_IN + (size_t)k * 8;
    } else {
        int j = id - 135168;
        int n = j >> 12, r = j & 4095;
        int h = 1 + (r >> 6);
        int w = ((r >> 5) & 1) * 65;
        int k = r & 31;
        off = (((size_t)(n*HP + h)) * WP + w) * C_IN + (size_t)k * 8;
    }
    uint4 z; z.x = z.y = z.z = z.w = 0u;
    *(uint4*)(qx + off) = z;
}

// ---------- x: fp32 NCHW -> exact-bf16 NHWC(+halo), lane-local quant blocks ----------
// A quant block (1h,16w,1c) = 64 contiguous bytes = ONE lane: load 4x dwordx4,
// amax/scale/quantize fully in-lane (no reduction, no serial phase). Single bf16
// LDS transpose [64c][66w] (pad 2 -> all patterns <=2-way) to NHWC 32B stores.
// Block = (n,h), loops cb=0..3 (4x coarsened). 2 barriers/iter, LDS 8.4 KB.
__global__ __launch_bounds__(256) void quant_x_kernel(const float* __restrict__ x,
                                                      unsigned short* __restrict__ qx) {
    __shared__ unsigned short xq[64][66];

    const int bid = blockIdx.x;             // 0..2047 = (n, h)
    const int n = bid >> 6;
    const int h = bid & 63;
    const int t = threadIdx.x;
    const int c_l = t >> 2;                 // 0..63  write-phase channel
    const int wq  = t & 3;                  // 16-w group
    const int wr  = t & 63;                 // read-phase w
    const int cg  = (t >> 6) * 16;          // read-phase c group (per wave)

    const float* srcb = x + (((size_t)(n*C_IN + c_l)) * HH + h) * WW + wq*16;
    unsigned short* dstb = qx + (((size_t)(n*HP + h + 1)) * WP + (wr + 1)) * C_IN + cg;

    for (int cb = 0; cb < 4; ++cb) {
        const float* src = srcb + (size_t)(cb*64) * (HH*WW);
        float v[16];
#pragma unroll
        for (int j = 0; j < 4; ++j) {
            float4 f = ((const float4*)src)[j];
            v[j*4+0]=f.x; v[j*4+1]=f.y; v[j*4+2]=f.z; v[j*4+3]=f.w;
        }
        float amax = 0.f;
#pragma unroll
        for (int k = 0; k < 16; ++k) amax = fmaxf(amax, fabsf(v[k]));
        float s, inv;
        blk_scale2(amax, s, inv);
#pragma unroll
        for (int k = 0; k < 8; ++k) {
            unsigned short lo = to_bf16_bits(copysignf(e2m1_mag(fabsf(v[2*k])   * inv) * s, v[2*k]));
            unsigned short hi = to_bf16_bits(copysignf(e2m1_mag(fabsf(v[2*k+1]) * inv) * s, v[2*k+1]));
            *(unsigned int*)&xq[c_l][wq*16 + 2*k] = ((unsigned int)hi << 16) | (unsigned int)lo;
        }
        __syncthreads();
        unsigned short outv[16];
#pragma unroll
        for (int i = 0; i < 16; ++i) outv[i] = xq[cg + i][wr];
        unsigned short* dst = dstb + cb*64;
        *(uint4*)(dst)     = *(const uint4*)&outv[0];
        *(uint4*)(dst + 8) = *(const uint4*)&outv[8];
        __syncthreads();
    }
}

// ---------- w: fp32 OIHW -> exact-bf16 [kpos][O][C], one block per o ----------
__global__ __launch_bounds__(256) void quant_w_kernel(const float* __restrict__ w,
                                                      unsigned short* __restrict__ qw) {
    __shared__ unsigned short lq[2304];   // one o-row, flat (ci*9 + p) order
    const int o = blockIdx.x;
    const int t = threadIdx.x;
    const float* src = w + (size_t)o * 2304;
    if (t < 144) {                        // 144 quant blocks of 16 per o
        float v[16];
#pragma unroll
        for (int j = 0; j < 4; ++j) {
            float4 f = ((const float4*)(src + t*16))[j];
            v[j*4+0]=f.x; v[j*4+1]=f.y; v[j*4+2]=f.z; v[j*4+3]=f.w;
        }
        float amax = 0.f;
#pragma unroll
        for (int j = 0; j < 16; ++j) amax = fmaxf(amax, fabsf(v[j]));
        float s, inv;
        blk_scale2(amax, s, inv);
#pragma unroll
        for (int j = 0; j < 16; ++j)
            lq[t*16 + j] = to_bf16_bits(copysignf(e2m1_mag(fabsf(v[j]) * inv) * s, v[j]));
    }
    __syncthreads();
#pragma unroll
    for (int p = 0; p < 9; ++p)
        qw[((size_t)(p*O_OUT + o)) * C_IN + t] = lq[t*9 + p];
}

// ---------- conv: implicit GEMM, 256x256 tile, BK=64, 4-phase, ALL ds_reads in-region ----------
// A = weights [O=256][K], B = pixels [256][K]; K = 36 K-tiles of 64. 8 waves (2M x 4N).
// LDS 128 KiB dbuf. T2 XOR-swizzle (linear gld_lds dest + inverse-swizzled global src).
//
// v5: no gap ds_reads at all. Staging round r of A covers LDS rows {32r..}+{128+32r..},
// i.e. fragment-read RDQ(q) depends on exactly round Ar_q. Issue order per tile:
//   PH0: Br0-3(t+1) | PH1: Ar0,Ar1(t+1) | PH2: Ar2,Ar3(t+1) | PH3: none
// In-region reads: PH0: Q1(t) | PH1: Q2(t) | PH2: Q3(t) | PH3: B(t+1) + Q0(t+1) (from stage buf)
// FIFO-verified waits (steady leftover entering tile = {Ar2,Ar3(t)}):
//   PH0 close vmcnt(5) -> drains Ar2(t)   (Q2 readable in PH1 region)
//   PH1 close vmcnt(6) -> drains Ar3(t)   (Q3 readable in PH2 region)
//   PH2 close vmcnt(3) -> drains Br0-3(t+1)+Ar0(t+1) (B(t+1),Q0(t+1) readable in PH3)
//   PH3 close vmcnt(2) -> drains Ar1(t+1) (Q1(t+1) readable in PH0(t+1) region)
// All slacks >= ~1.2 phases; never drains to 0; MFMA sequence bit-identical to v4.
__device__ __forceinline__ void gld16(void* lds, const void* g) {
    __builtin_amdgcn_global_load_lds(
        (const __attribute__((address_space(1))) unsigned int*)g,
        (__attribute__((address_space(3))) unsigned int*)lds,
        16, 0, 0);
}

__device__ __forceinline__ short8 rd8(const void* p) {
    return *(const short8*)p;
}

#define MFMA16 __builtin_amdgcn_mfma_f32_16x16x32_bf16

// accumulate quadrant I0 (rows) x all 4 b-columns; k-slice order 0 then 1 (bit-exact)
#define MM16(I0, A00, A01, A10, A11, B)                                   \
    do {                                                                  \
        _Pragma("unroll")                                                 \
        for (int j = 0; j < 4; ++j) {                                     \
            acc[I0][j]     = MFMA16(A00, B[j][0], acc[I0][j],     0,0,0); \
            acc[I0][j]     = MFMA16(A01, B[j][1], acc[I0][j],     0,0,0); \
            acc[(I0)+1][j] = MFMA16(A10, B[j][0], acc[(I0)+1][j], 0,0,0); \
            acc[(I0)+1][j] = MFMA16(A11, B[j][1], acc[(I0)+1][j], 0,0,0); \
        }                                                                 \
    } while (0)

// load A-quadrant Q into 4 named regs from buffer BASE
#define RDQB(D0, D1, D2, D3, BASE, Q)                                     \
    D0 = rd8((BASE) + rA + (2*(Q))*2048   + cA0);                         \
    D1 = rd8((BASE) + rA + (2*(Q))*2048   + (cA0^64));                    \
    D2 = rd8((BASE) + rA + (2*(Q)+1)*2048 + cA0);                         \
    D3 = rd8((BASE) + rA + (2*(Q)+1)*2048 + (cA0^64));

#define PH_OPEN()                                                         \
    __builtin_amdgcn_s_barrier();                                         \
    asm volatile("s_waitcnt lgkmcnt(0)" ::: "memory");                    \
    __builtin_amdgcn_sched_barrier(0);                                    \
    __builtin_amdgcn_s_setprio(1);

#define PH_CLOSE(VM)                                                      \
    __builtin_amdgcn_s_setprio(0);                                        \
    asm volatile("s_waitcnt " VM ::: "memory");                           \
    __builtin_amdgcn_s_barrier();

// one K-tile: compute from buffer at LAOFF, stage tile TN into LAOFF^65536.
// BCUR consumed; BNXT filled in PH3. aA holds Q0(t) on entry; holds Q0(t+1) on exit.
#define CONV_TILE(TN, LAOFF, BCUR, BNXT)                                  \
    do {                                                                  \
        const int tn  = (TN);                                             \
        const int pn  = tn >> 2;                                          \
        const int qn  = pn / 3;                                           \
        const int dwn = pn - qn * 3;                                      \
        const int cn  = (tn & 3) << 6;                                    \
        const unsigned short* ga = gA + pn * 65536 + cn;                  \
        const unsigned short* gb = gB + (ptrdiff_t)((qn - 1) * WP + (dwn - 1)) * C_IN + cn; \
        const char* LA = Lc + (LAOFF);                                    \
        char* SA = Lc + ((LAOFF) ^ 65536);                                \
        char* SB = SA + 32768;                                            \
        /* PH0: compute Q0 x BCUR; in-region read Q1; issue all 4 B rounds */ \
        gld16(SB + bwb,         gb);                                      \
        gld16(SB + bwb + 8192,  gb + 16896);                              \
        gld16(SB + bwb + 16384, gb + 2*16896);                            \
        gld16(SB + bwb + 24576, gb + 3*16896);                            \
        PH_OPEN();                                                        \
        RDQB(aB0, aB1, aB2, aB3, LA, 1);                                  \
        MM16(0, aA0, aA1, aA2, aA3, BCUR);                                \
        PH_CLOSE("vmcnt(5)");                                             \
        /* PH1: compute Q1; in-region read Q2; issue Ar0,Ar1 */           \
        gld16(SA + awb,        ga);                                       \
        gld16(SA + awb + 4096, ga + 8192);                                \
        PH_OPEN();                                                        \
        RDQB(aA0, aA1, aA2, aA3, LA, 2);                                  \
        MM16(2, aB0, aB1, aB2, aB3, BCUR);                                \
        PH_CLOSE("vmcnt(6)");                                             \
        /* PH2: compute Q2; in-region read Q3; issue Ar2,Ar3 */           \
        gld16(SA + awb + 8192,  ga + 16384);                              \
        gld16(SA + awb + 12288, ga + 24576);                              \
        PH_OPEN();                                                        \
        RDQB(aB0, aB1, aB2, aB3, LA, 3);                                  \
        MM16(4, aA0, aA1, aA2, aA3, BCUR);                                \
        PH_CLOSE("vmcnt(3)");                                             \
        /* PH3: compute Q3 x BCUR; in-region read B(t+1)->BNXT and Q0(t+1)->aA */ \
        PH_OPEN();                                                        \
        _Pragma("unroll")                                                 \
        for (int j = 0; j < 4; ++j) {                                     \
            BNXT[j][0] = rd8(SB + rB + j*2048 + cA0);                     \
            BNXT[j][1] = rd8(SB + rB + j*2048 + (cA0^64));                \
        }                                                                 \
        RDQB(aA0, aA1, aA2, aA3, SA, 0);                                  \
        MM16(6, aB0, aB1, aB2, aB3, BCUR);                                \
        PH_CLOSE("vmcnt(2)");                                             \
    } while (0)

__global__ __launch_bounds__(512) void conv_kernel(const unsigned short* __restrict__ qw,
                                                   const unsigned short* __restrict__ qx,
                                                   float* __restrict__ out) {
    __shared__ unsigned short lds[65536];     // 128 KiB: [A0|B0|A1|B1], 32 KiB each
    char* Lc = (char*)lds;

    const int tid  = threadIdx.x;
    const int w    = tid >> 6;
    const int lane = tid & 63;
    const int lo16 = lane & 15;
    const int quad = lane >> 4;
    const int wm   = w & 1;                   // 2 waves in M
    const int wn   = w >> 1;                  // 4 waves in N

    // XCD swizzle: blocks with id%8==x land on XCD x (round-robin dispatch)
    const int id  = blockIdx.x;               // 0..511
    const int idx = id >> 3;                  // 0..63
    const int n   = (id & 7) + ((idx >> 4) << 3);
    const int pt  = idx & 15;                 // pixel tile within image
    const int h0  = pt * 4;
    const int hw0 = pt * 256;

    // ---- staging (write-side) precompute: linear LDS dest, inverse-swizzled src ----
    const int trow  = tid >> 3;                              // 0..63 (8 lanes per row)
    const int c_off = ((tid & 7) ^ (trow & 7)) << 3;         // swizzled source col (elems)
    const unsigned short* gB = qx + ((size_t)((n*HP + h0 + 1) * WP + trow + 1)) * C_IN + c_off;
    const int ro0 = trow + ((tid >= 256) ? 96 : 0);          // A quadrant-major row map
    const unsigned short* gA = qw + (size_t)ro0 * C_IN + c_off;
    const int awb = w * 1024 + ((w < 4) ? 0 : 12288);        // A stage lds byte base
    const int bwb = w * 1024;                                // B stage lds byte base

    // ---- read-side precompute (same XOR) ----
    const int key = (lo16 & 7) << 4;
    const int cA0 = (quad << 4) ^ key;                       // ks=0 col byte; ks=1 = cA0^64
    const int rA  = (wm * 128 + lo16) * 128;                 // + i*2048
    const int rB  = (wn * 64  + lo16) * 128;                 // + j*2048

    f32x4 acc[8][4];
#pragma unroll
    for (int i = 0; i < 8; ++i)
#pragma unroll
        for (int j = 0; j < 4; ++j)
            acc[i][j] = (f32x4){0.f, 0.f, 0.f, 0.f};

    // ---- prologue: stage K-tile 0 (p=0: dh=-1,dw=-1, c0=0) into buf0, full drain ----
    {
        const unsigned short* ga = gA;
        const unsigned short* gb = gB - 17152;               // (-66-1)*256
        char* SA = Lc;
        char* SB = Lc + 32768;
        gld16(SB + bwb,         gb);
        gld16(SB + bwb + 8192,  gb + 16896);
        gld16(SB + bwb + 16384, gb + 2*16896);
        gld16(SB + bwb + 24576, gb + 3*16896);
        gld16(SA + awb,         ga);
        gld16(SA + awb + 4096,  ga + 8192);
        gld16(SA + awb + 8192,  ga + 16384);
        gld16(SA + awb + 12288, ga + 24576);
        asm volatile("s_waitcnt vmcnt(0)" ::: "memory");
        __builtin_amdgcn_s_barrier();
    }

    // preload B(t=0) fragments and Q0(t=0) from buf0
    short8 aA0, aA1, aA2, aA3, aB0, aB1, aB2, aB3;
    short8 b0[4][2], b1[4][2];
    {
        const char* LB = Lc + 32768;
#pragma unroll
        for (int j = 0; j < 4; ++j) {
            b0[j][0] = rd8(LB + rB + j*2048 + cA0);
            b0[j][1] = rd8(LB + rB + j*2048 + (cA0^64));
        }
        const char* LA = Lc;
        RDQB(aA0, aA1, aA2, aA3, LA, 0);
    }

#pragma unroll 1
    for (int tt = 0; tt < 18; ++tt) {
        const int t0 = tt * 2;
        // even tile: compute buf0, stage (t0+1) into buf1; consume b0, fill b1
        CONV_TILE(t0 + 1, 0, b0, b1);
        // odd tile: compute buf1, stage (t0+2, clamped) into buf0; consume b1, fill b0
        CONV_TILE((t0 + 2 < 36) ? (t0 + 2) : 35, 65536, b1, b0);
    }

    // drain leftover stage loads before epilogue (LDS writes in flight)
    asm volatile("s_waitcnt vmcnt(0)" ::: "memory");

    // ---- epilogue: same C/D mapping as verified kernel ----
#pragma unroll
    for (int i = 0; i < 8; ++i) {
        const int o = wm * 128 + i * 16 + quad * 4;
        float* orow = out + ((size_t)(n * O_OUT + o)) * (HH*WW) + hw0 + wn * 64 + lo16;
#pragma unroll
        for (int j = 0; j < 4; ++j) {
            float* dst = orow + j * 16;
#pragma unroll
            for (int r = 0; r < 4; ++r)
                dst[(size_t)r * (HH*WW)] = acc[i][j][r];
        }
    }
}

extern "C" void kernel_launch(void* const* d_in, const int* in_sizes, int n_in,
                              void* d_out, int out_size, void* d_ws, size_t ws_size,
                              hipStream_t stream) {
    const float* x = (const float*)d_in[0];
    const float* w = (const float*)d_in[1];
    float* out = (float*)d_out;

    unsigned short* qx = (unsigned short*)d_ws;                       // padded NHWC bf16
    unsigned short* qw = (unsigned short*)((char*)d_ws + QX_BYTES);   // [9][O][C] bf16

    halo_zero_kernel<<<dim3(1040), 256, 0, stream>>>(qx);
    quant_x_kernel<<<dim3(N_IMG*HH), 256, 0, stream>>>(x, qx);
    quant_w_kernel<<<dim3(O_OUT), 256, 0, stream>>>(w, qw);
    conv_kernel<<<dim3(512), 512, 0, stream>>>(qw, qx, out);
}

// Round 5
// 357.652 us; speedup vs baseline: 1.0031x; 1.0031x over previous
//
#include <hip/hip_runtime.h>
#include <stdint.h>
#include <stddef.h>

typedef __attribute__((ext_vector_type(8))) short short8;
typedef __attribute__((ext_vector_type(4))) float f32x4;

#define N_IMG 32
#define C_IN  256
#define HH    64
#define WW    64
#define O_OUT 256
#define HP    66
#define WP    66

#define QX_ELEMS (N_IMG*HP*WP*C_IN)      // 35,684,352
#define QX_BYTES ((size_t)QX_ELEMS*2)    // 71,368,704
#define QW_ELEMS (9*O_OUT*C_IN)          // 589,824

// ---------- quantization helpers (match jnp reference bit-for-bit) ----------

// nearest E2M1 magnitude; ties round up (jnp.digitize right=False: a==mid -> upper)
__device__ __forceinline__ float e2m1_mag(float a) {
    return a < 0.25f ? 0.0f
         : a < 0.75f ? 0.5f
         : a < 1.25f ? 1.0f
         : a < 1.75f ? 1.5f
         : a < 2.5f  ? 2.0f
         : a < 3.5f  ? 3.0f
         : a < 5.0f  ? 4.0f : 6.0f;
}

// scale = 2^ceil(log2(max(amax,1e-30)/6)), or 1.0 if amax==0; also exact 1/scale.
__device__ __forceinline__ void blk_scale2(float amax, float& s, float& inv) {
    float ac = fmaxf(amax, 1e-30f);
    int e;
    float m = frexpf(ac, &e);
    int ex = (m > 0.75f) ? (e - 2) : (e - 3);
    if (amax > 0.0f) { s = ldexpf(1.0f, ex); inv = ldexpf(1.0f, -ex); }
    else             { s = 1.0f; inv = 1.0f; }
}

// E2M1-grid * pow2 -> 1 mantissa bit -> exact in bf16 (truncate == round)
__device__ __forceinline__ unsigned short to_bf16_bits(float v) {
    union { float f; unsigned int u; } cv; cv.f = v;
    return (unsigned short)(cv.u >> 16);
}

// ---------- x: fp32 NCHW -> exact-bf16 NHWC(+halo), one-pass 256-ch LDS transpose ----
// Block = (n,h). Thread t owns channel c=t: reads x[n][c][h][0..63] (256B contiguous),
// quantizes 4 blocks of 16 lane-locally, scatters 64 u16 into a [64w][128dw] XOR-
// swizzled LDS tile (d ^= (w&7)<<2): write-side 2-way, read-side b128 2-way (volume-
// optimal). Phase 2: thread (pix=t>>2, seg=t&3) reads 8x b128 and stores 128B of the
// pixel's 512B NHWC record -> each wave's 8 stores tile a contiguous 8 KB (dense
// 16B/lane @128B stride per instr). Single barrier, no cb loop, LDS 32 KB.
__global__ __launch_bounds__(256) void quant_x_kernel(const float* __restrict__ x,
                                                      unsigned short* __restrict__ qx) {
    __shared__ unsigned int xq[8192];            // [64 w][128 dwords] swizzled
    unsigned short* xq16 = (unsigned short*)xq;

    const int bid = blockIdx.x;                  // 0..2047 = (n, h)
    const int n = bid >> 6, h = bid & 63;
    const int t = threadIdx.x;                   // = channel c

    const float* src = x + (((size_t)(n*C_IN + t)) * HH + h) * WW;
    const int dbase = t >> 1, half = t & 1;

#pragma unroll
    for (int b = 0; b < 4; ++b) {
        float v[16];
#pragma unroll
        for (int j = 0; j < 4; ++j) {
            float4 f = ((const float4*)src)[b*4 + j];
            v[j*4+0]=f.x; v[j*4+1]=f.y; v[j*4+2]=f.z; v[j*4+3]=f.w;
        }
        float amax = 0.f;
#pragma unroll
        for (int k = 0; k < 16; ++k) amax = fmaxf(amax, fabsf(v[k]));
        float s, inv;
        blk_scale2(amax, s, inv);
#pragma unroll
        for (int k = 0; k < 16; ++k) {
            const int wrow = b*16 + k;
            unsigned short qv = to_bf16_bits(copysignf(e2m1_mag(fabsf(v[k]) * inv) * s, v[k]));
            const int d = dbase ^ ((wrow & 7) << 2);
            xq16[wrow*256 + d*2 + half] = qv;
        }
    }
    __syncthreads();

    const int pix = t >> 2, seg = t & 3;
    unsigned short* dst = qx + (((size_t)(n*HP + h + 1)) * WP + (pix + 1)) * C_IN + seg*64;
    const unsigned int* rowp = xq + pix*128;
    const int px7 = pix & 7;
#pragma unroll
    for (int r = 0; r < 8; ++r) {
        const int gs = (seg*8 + r) ^ px7;        // XOR touches only low-3 (r) bits
        uint4 d4 = *(const uint4*)(rowp + gs*4);
        *(uint4*)(dst + r*8) = d4;
    }
}

// ---------- w-quant + qx halo-zero fused (uniform per-block branch) ----------
// blocks 0..255: fp32 OIHW -> exact-bf16 [kpos][O][C] (one block per o)
// blocks 256..1295: zero the 4.3 MB qx border (replaces separate halo kernel)
__global__ __launch_bounds__(256) void quant_w_halo_kernel(const float* __restrict__ w,
                                                           unsigned short* __restrict__ qw,
                                                           unsigned short* __restrict__ qx) {
    const int b = blockIdx.x;
    const int t = threadIdx.x;
    if (b >= O_OUT) {
        int id = (b - O_OUT) * 256 + t;
        size_t off;
        if (id < 135168) {
            int n = id / 4224, r = id % 4224;
            int h = (r / 2112) * 65;
            int k = r % 2112;
            off = (((size_t)(n*HP + h)) * WP) * C_IN + (size_t)k * 8;
        } else {
            int j = id - 135168;
            int n = j >> 12, r = j & 4095;
            int h = 1 + (r >> 6);
            int ww = ((r >> 5) & 1) * 65;
            int k = r & 31;
            off = (((size_t)(n*HP + h)) * WP + ww) * C_IN + (size_t)k * 8;
        }
        uint4 z; z.x = z.y = z.z = z.w = 0u;
        *(uint4*)(qx + off) = z;
        return;
    }
    __shared__ unsigned short lq[2304];   // one o-row, flat (ci*9 + p) order
    const int o = b;
    const float* src = w + (size_t)o * 2304;
    if (t < 144) {                        // 144 quant blocks of 16 per o
        float v[16];
#pragma unroll
        for (int j = 0; j < 4; ++j) {
            float4 f = ((const float4*)(src + t*16))[j];
            v[j*4+0]=f.x; v[j*4+1]=f.y; v[j*4+2]=f.z; v[j*4+3]=f.w;
        }
        float amax = 0.f;
#pragma unroll
        for (int j = 0; j < 16; ++j) amax = fmaxf(amax, fabsf(v[j]));
        float s, inv;
        blk_scale2(amax, s, inv);
#pragma unroll
        for (int j = 0; j < 16; ++j)
            lq[t*16 + j] = to_bf16_bits(copysignf(e2m1_mag(fabsf(v[j]) * inv) * s, v[j]));
    }
    __syncthreads();
#pragma unroll
    for (int p = 0; p < 9; ++p)
        qw[((size_t)(p*O_OUT + o)) * C_IN + t] = lq[t*9 + p];
}

// ---------- conv: implicit GEMM, 256x256 tile, BK=64, 4-phase, SINGLE barrier/phase ----
// A = weights [O=256][K], B = pixels [256][K]; K = 36 K-tiles of 64. 8 waves (2M x 4N).
// LDS 128 KiB dbuf. T2 XOR-swizzle (linear gld_lds dest + inverse-swizzled global src).
//
// v6: one s_barrier per phase (drop the redundant open-barrier). Safety: with the LDS
// double-buffer, 1 barrier/phase bounds wave drift to 1 phase; drift-1 is safe
// (a wave ahead in PH0(t+1) gld-stores into buf P while laggards in PH3(t) ds_read
// buf Q; checked for all 4 boundaries). Cross-wave staged-data visibility: every
// reader sits after the barrier that follows the staging waves' vmcnt drain.
// Issue order per tile: PH0: Br0-3(t+1) | PH1: Ar0,Ar1(t+1) | PH2: Ar2,Ar3(t+1) | PH3: -
// In-region ds_reads: PH0: Q1(t) | PH1: Q2(t) | PH2: Q3(t) | PH3: B(t+1)+Q0(t+1)
// FIFO-verified waits (steady leftover entering tile = {Ar2,Ar3(t)}):
//   PH0 vmcnt(5) -> Ar2(t) | PH1 vmcnt(6) -> Ar3(t) | PH2 vmcnt(3) -> Br0-3+Ar0(t+1)
//   PH3 vmcnt(2) -> Ar1(t+1). Never drains to 0; MFMA sequence bit-identical.
__device__ __forceinline__ void gld16(void* lds, const void* g) {
    __builtin_amdgcn_global_load_lds(
        (const __attribute__((address_space(1))) unsigned int*)g,
        (__attribute__((address_space(3))) unsigned int*)lds,
        16, 0, 0);
}

__device__ __forceinline__ short8 rd8(const void* p) {
    return *(const short8*)p;
}

#define MFMA16 __builtin_amdgcn_mfma_f32_16x16x32_bf16

// accumulate quadrant I0 (rows) x all 4 b-columns; k-slice order 0 then 1 (bit-exact)
#define MM16(I0, A00, A01, A10, A11, B)                                   \
    do {                                                                  \
        _Pragma("unroll")                                                 \
        for (int j = 0; j < 4; ++j) {                                     \
            acc[I0][j]     = MFMA16(A00, B[j][0], acc[I0][j],     0,0,0); \
            acc[I0][j]     = MFMA16(A01, B[j][1], acc[I0][j],     0,0,0); \
            acc[(I0)+1][j] = MFMA16(A10, B[j][0], acc[(I0)+1][j], 0,0,0); \
            acc[(I0)+1][j] = MFMA16(A11, B[j][1], acc[(I0)+1][j], 0,0,0); \
        }                                                                 \
    } while (0)

// load A-quadrant Q into 4 named regs from buffer BASE
#define RDQB(D0, D1, D2, D3, BASE, Q)                                     \
    D0 = rd8((BASE) + rA + (2*(Q))*2048   + cA0);                         \
    D1 = rd8((BASE) + rA + (2*(Q))*2048   + (cA0^64));                    \
    D2 = rd8((BASE) + rA + (2*(Q)+1)*2048 + cA0);                         \
    D3 = rd8((BASE) + rA + (2*(Q)+1)*2048 + (cA0^64));

#define PH_START()                                                        \
    asm volatile("s_waitcnt lgkmcnt(0)" ::: "memory");                    \
    __builtin_amdgcn_sched_barrier(0);                                    \
    __builtin_amdgcn_s_setprio(1);

#define PH_BOUND(VM)                                                      \
    __builtin_amdgcn_s_setprio(0);                                        \
    asm volatile("s_waitcnt " VM ::: "memory");                           \
    __builtin_amdgcn_s_barrier();

// one K-tile: compute from buffer at LAOFF, stage tile TN into LAOFF^65536.
// BCUR consumed; BNXT filled in PH3. aA holds Q0(t) on entry; Q0(t+1) on exit.
#define CONV_TILE(TN, LAOFF, BCUR, BNXT)                                  \
    do {                                                                  \
        const int tn  = (TN);                                             \
        const int pn  = tn >> 2;                                          \
        const int qn  = pn / 3;                                           \
        const int dwn = pn - qn * 3;                                      \
        const int cn  = (tn & 3) << 6;                                    \
        const unsigned short* ga = gA + pn * 65536 + cn;                  \
        const unsigned short* gb = gB + (ptrdiff_t)((qn - 1) * WP + (dwn - 1)) * C_IN + cn; \
        const char* LA = Lc + (LAOFF);                                    \
        char* SA = Lc + ((LAOFF) ^ 65536);                                \
        char* SB = SA + 32768;                                            \
        /* PH0: compute Q0 x BCUR; in-region read Q1; issue all 4 B rounds */ \
        gld16(SB + bwb,         gb);                                      \
        gld16(SB + bwb + 8192,  gb + 16896);                              \
        gld16(SB + bwb + 16384, gb + 2*16896);                            \
        gld16(SB + bwb + 24576, gb + 3*16896);                            \
        PH_START();                                                       \
        RDQB(aB0, aB1, aB2, aB3, LA, 1);                                  \
        MM16(0, aA0, aA1, aA2, aA3, BCUR);                                \
        PH_BOUND("vmcnt(5)");                                             \
        /* PH1: compute Q1; in-region read Q2; issue Ar0,Ar1 */           \
        gld16(SA + awb,        ga);                                       \
        gld16(SA + awb + 4096, ga + 8192);                                \
        PH_START();                                                       \
        RDQB(aA0, aA1, aA2, aA3, LA, 2);                                  \
        MM16(2, aB0, aB1, aB2, aB3, BCUR);                                \
        PH_BOUND("vmcnt(6)");                                             \
        /* PH2: compute Q2; in-region read Q3; issue Ar2,Ar3 */           \
        gld16(SA + awb + 8192,  ga + 16384);                              \
        gld16(SA + awb + 12288, ga + 24576);                              \
        PH_START();                                                       \
        RDQB(aB0, aB1, aB2, aB3, LA, 3);                                  \
        MM16(4, aA0, aA1, aA2, aA3, BCUR);                                \
        PH_BOUND("vmcnt(3)");                                             \
        /* PH3: compute Q3 x BCUR; in-region read B(t+1)->BNXT and Q0(t+1)->aA */ \
        PH_START();                                                       \
        _Pragma("unroll")                                                 \
        for (int j = 0; j < 4; ++j) {                                     \
            BNXT[j][0] = rd8(SB + rB + j*2048 + cA0);                     \
            BNXT[j][1] = rd8(SB + rB + j*2048 + (cA0^64));                \
        }                                                                 \
        RDQB(aA0, aA1, aA2, aA3, SA, 0);                                  \
        MM16(6, aB0, aB1, aB2, aB3, BCUR);                                \
        PH_BOUND("vmcnt(2)");                                             \
    } while (0)

__global__ __launch_bounds__(512) void conv_kernel(const unsigned short* __restrict__ qw,
                                                   const unsigned short* __restrict__ qx,
                                                   float* __restrict__ out) {
    __shared__ unsigned short lds[65536];     // 128 KiB: [A0|B0|A1|B1], 32 KiB each
    char* Lc = (char*)lds;

    const int tid  = threadIdx.x;
    const int w    = tid >> 6;
    const int lane = tid & 63;
    const int lo16 = lane & 15;
    const int quad = lane >> 4;
    const int wm   = w & 1;                   // 2 waves in M
    const int wn   = w >> 1;                  // 4 waves in N

    // XCD swizzle: blocks with id%8==x land on XCD x (round-robin dispatch)
    const int id  = blockIdx.x;               // 0..511
    const int idx = id >> 3;                  // 0..63
    const int n   = (id & 7) + ((idx >> 4) << 3);
    const int pt  = idx & 15;                 // pixel tile within image
    const int h0  = pt * 4;
    const int hw0 = pt * 256;

    // ---- staging (write-side) precompute: linear LDS dest, inverse-swizzled src ----
    const int trow  = tid >> 3;                              // 0..63 (8 lanes per row)
    const int c_off = ((tid & 7) ^ (trow & 7)) << 3;         // swizzled source col (elems)
    const unsigned short* gB = qx + ((size_t)((n*HP + h0 + 1) * WP + trow + 1)) * C_IN + c_off;
    const int ro0 = trow + ((tid >= 256) ? 96 : 0);          // A quadrant-major row map
    const unsigned short* gA = qw + (size_t)ro0 * C_IN + c_off;
    const int awb = w * 1024 + ((w < 4) ? 0 : 12288);        // A stage lds byte base
    const int bwb = w * 1024;                                // B stage lds byte base

    // ---- read-side precompute (same XOR) ----
    const int key = (lo16 & 7) << 4;
    const int cA0 = (quad << 4) ^ key;                       // ks=0 col byte; ks=1 = cA0^64
    const int rA  = (wm * 128 + lo16) * 128;                 // + i*2048
    const int rB  = (wn * 64  + lo16) * 128;                 // + j*2048

    f32x4 acc[8][4];
#pragma unroll
    for (int i = 0; i < 8; ++i)
#pragma unroll
        for (int j = 0; j < 4; ++j)
            acc[i][j] = (f32x4){0.f, 0.f, 0.f, 0.f};

    // ---- prologue: stage K-tile 0 (p=0: dh=-1,dw=-1, c0=0) into buf0, full drain ----
    {
        const unsigned short* ga = gA;
        const unsigned short* gb = gB - 17152;               // (-66-1)*256
        char* SA = Lc;
        char* SB = Lc + 32768;
        gld16(SB + bwb,         gb);
        gld16(SB + bwb + 8192,  gb + 16896);
        gld16(SB + bwb + 16384, gb + 2*16896);
        gld16(SB + bwb + 24576, gb + 3*16896);
        gld16(SA + awb,         ga);
        gld16(SA + awb + 4096,  ga + 8192);
        gld16(SA + awb + 8192,  ga + 16384);
        gld16(SA + awb + 12288, ga + 24576);
        asm volatile("s_waitcnt vmcnt(0)" ::: "memory");
        __builtin_amdgcn_s_barrier();
    }

    // preload B(t=0) fragments and Q0(t=0) from buf0
    short8 aA0, aA1, aA2, aA3, aB0, aB1, aB2, aB3;
    short8 b0[4][2], b1[4][2];
    {
        const char* LB = Lc + 32768;
#pragma unroll
        for (int j = 0; j < 4; ++j) {
            b0[j][0] = rd8(LB + rB + j*2048 + cA0);
            b0[j][1] = rd8(LB + rB + j*2048 + (cA0^64));
        }
        const char* LA = Lc;
        RDQB(aA0, aA1, aA2, aA3, LA, 0);
    }

#pragma unroll 1
    for (int tt = 0; tt < 18; ++tt) {
        const int t0 = tt * 2;
        // even tile: compute buf0, stage (t0+1) into buf1; consume b0, fill b1
        CONV_TILE(t0 + 1, 0, b0, b1);
        // odd tile: compute buf1, stage (t0+2, clamped) into buf0; consume b1, fill b0
        CONV_TILE((t0 + 2 < 36) ? (t0 + 2) : 35, 65536, b1, b0);
    }

    // drain leftover stage loads before epilogue (LDS writes in flight)
    asm volatile("s_waitcnt vmcnt(0)" ::: "memory");

    // ---- epilogue: same C/D mapping as verified kernel ----
#pragma unroll
    for (int i = 0; i < 8; ++i) {
        const int o = wm * 128 + i * 16 + quad * 4;
        float* orow = out + ((size_t)(n * O_OUT + o)) * (HH*WW) + hw0 + wn * 64 + lo16;
#pragma unroll
        for (int j = 0; j < 4; ++j) {
            float* dst = orow + j * 16;
#pragma unroll
            for (int r = 0; r < 4; ++r)
                dst[(size_t)r * (HH*WW)] = acc[i][j][r];
        }
    }
}

extern "C" void kernel_launch(void* const* d_in, const int* in_sizes, int n_in,
                              void* d_out, int out_size, void* d_ws, size_t ws_size,
                              hipStream_t stream) {
    const float* x = (const float*)d_in[0];
    const float* w = (const float*)d_in[1];
    float* out = (float*)d_out;

    unsigned short* qx = (unsigned short*)d_ws;                       // padded NHWC bf16
    unsigned short* qw = (unsigned short*)((char*)d_ws + QX_BYTES);   // [9][O][C] bf16

    quant_w_halo_kernel<<<dim3(O_OUT + 1040), 256, 0, stream>>>(w, qw, qx);
    quant_x_kernel<<<dim3(N_IMG*HH), 256, 0, stream>>>(x, qx);
    conv_kernel<<<dim3(512), 512, 0, stream>>>(qw, qx, out);
}